// Round 3
// baseline (723.323 us; speedup 1.0000x reference)
//
#include <hip/hip_runtime.h>
#include <hip/hip_bf16.h>
#include <math.h>

typedef __hip_bfloat16 bf16;

#define NPIX 4096

__device__ __forceinline__ float b2f(bf16 v) { return __bfloat162float(v); }
__device__ __forceinline__ float ldf(const bf16* p, int i) { return __bfloat162float(p[i]); }
__device__ __forceinline__ float ldf(const float* p, int i) { return p[i]; }

// Load 24 contiguous bf16 (48 bytes, 16B-aligned) -> 24 floats.
__device__ __forceinline__ void load24(const bf16* __restrict__ src, float* dst) {
    const uint4* s = (const uint4*)src;
#pragma unroll
    for (int c = 0; c < 3; ++c) {
        uint4 u = s[c];
        dst[c * 8 + 0] = __uint_as_float(u.x << 16);
        dst[c * 8 + 1] = __uint_as_float(u.x & 0xFFFF0000u);
        dst[c * 8 + 2] = __uint_as_float(u.y << 16);
        dst[c * 8 + 3] = __uint_as_float(u.y & 0xFFFF0000u);
        dst[c * 8 + 4] = __uint_as_float(u.z << 16);
        dst[c * 8 + 5] = __uint_as_float(u.z & 0xFFFF0000u);
        dst[c * 8 + 6] = __uint_as_float(u.w << 16);
        dst[c * 8 + 7] = __uint_as_float(u.w & 0xFFFF0000u);
    }
}

// ---------------- dtype detector: bf16 vs fp32 input buffers ----------------
// Samples even uint16s of q. bf16 data: each is a bf16 of ~N(0,1) -> exponent
// field in [100,135] nearly always. fp32 data: even uint16 = low mantissa half
// -> random (~14% hit) or exactly 0 if the fp32 values are bf16-quantized.
__global__ void detect_kernel(const unsigned short* __restrict__ qraw, int* __restrict__ flagp)
{
    __shared__ int cnt;
    if (threadIdx.x == 0) cnt = 0;
    __syncthreads();
    unsigned short u = qraw[threadIdx.x * 2];
    int e = (u >> 7) & 0xFF;
    if (e >= 100 && e <= 135) atomicAdd(&cnt, 1);
    __syncthreads();
    if (threadIdx.x == 0) flagp[0] = (cnt > 128) ? 1 : 0;
}

// ---------------- convert 26 small tensors (weights/biases/flows) to fp32 ----------------
struct CArgs {
    const void* src[26];
    int dstoff[26];
    int n[26];
};

__global__ void convert_kernel(CArgs a, const int* __restrict__ flagp, float* __restrict__ cw)
{
    const int t = blockIdx.y;
    const int n = a.n[t];
    float* d = cw + a.dstoff[t];
    if (flagp[0]) {
        const bf16* s = (const bf16*)a.src[t];
        for (int i = blockIdx.x * 256 + threadIdx.x; i < n; i += 256 * gridDim.x) d[i] = b2f(s[i]);
    } else {
        const float* s = (const float*)a.src[t];
        for (int i = blockIdx.x * 256 + threadIdx.x; i < n; i += 256 * gridDim.x) d[i] = s[i];
    }
}

// ---------------- conv1: 1x1, 436 -> 64, virtual concat, lrelu ----------------
template <typename T>
__device__ __forceinline__ void conv1_acc(const T* __restrict__ q, const T* __restrict__ v0,
                                          const T* __restrict__ v1, int p,
                                          const float* __restrict__ wsm, float* acc)
{
    for (int i = 0; i < 144; ++i) {
        float a = ldf(q, i * NPIX + p);
        const float* wr = &wsm[i * 16];
#pragma unroll
        for (int j = 0; j < 16; ++j) acc[j] += a * wr[j];
    }
    for (int i = 0; i < 144; ++i) {
        float a = ldf(v0, i * NPIX + p);
        const float* wr = &wsm[(144 + i) * 16];
#pragma unroll
        for (int j = 0; j < 16; ++j) acc[j] += a * wr[j];
    }
    for (int i = 0; i < 144; ++i) {
        float a = ldf(v1, i * NPIX + p);
        const float* wr = &wsm[(288 + i) * 16];
#pragma unroll
        for (int j = 0; j < 16; ++j) acc[j] += a * wr[j];
    }
}

__global__ void conv1_kernel(const void* __restrict__ q, const void* __restrict__ v0,
                             const void* __restrict__ v1, const float* __restrict__ fl0,
                             const float* __restrict__ fl1, const float* __restrict__ w,
                             const float* __restrict__ b, const int* __restrict__ flagp,
                             float* __restrict__ out)
{
    __shared__ float wsm[436 * 16];
    const int tid = threadIdx.x;
    const int obase = blockIdx.y * 16;
    for (int idx = tid; idx < 436 * 16; idx += 256) {
        int i = idx >> 4, j = idx & 15;
        wsm[idx] = w[(obase + j) * 436 + i];   // wsm[i*16+j]
    }
    __syncthreads();
    const int p = blockIdx.x * 256 + tid;
    float acc[16];
#pragma unroll
    for (int j = 0; j < 16; ++j) acc[j] = b[obase + j];
    if (flagp[0]) conv1_acc<bf16>((const bf16*)q, (const bf16*)v0, (const bf16*)v1, p, wsm, acc);
    else          conv1_acc<float>((const float*)q, (const float*)v0, (const float*)v1, p, wsm, acc);
    // flow channels 432..435 (fp32 converted)
    float fa[4] = { fl0[p], fl0[NPIX + p], fl1[p], fl1[NPIX + p] };
#pragma unroll
    for (int i = 0; i < 4; ++i) {
        const float* wr = &wsm[(432 + i) * 16];
#pragma unroll
        for (int j = 0; j < 16; ++j) acc[j] += fa[i] * wr[j];
    }
#pragma unroll
    for (int j = 0; j < 16; ++j) {
        float v = acc[j];
        out[(obase + j) * NPIX + p] = (v >= 0.f) ? v : 0.1f * v;
    }
}

// ---------------- conv 3x3, 64 -> 64, pad 1, lrelu ----------------
__global__ void conv3_kernel(const float* __restrict__ in, const float* __restrict__ w,
                             const float* __restrict__ b, float* __restrict__ out)
{
    __shared__ float wsm[576];
    const int tid = threadIdx.x;
    const int co = blockIdx.y;
    for (int idx = tid; idx < 576; idx += 256) wsm[idx] = w[co * 576 + idx];
    __syncthreads();
    const int p = blockIdx.x * 256 + tid;
    const int y = p >> 6, x = p & 63;
    float acc = b[co];
    for (int ci = 0; ci < 64; ++ci) {
        const float* ib = in + ci * NPIX;
        const float* wr = &wsm[ci * 9];
#pragma unroll
        for (int dy = -1; dy <= 1; ++dy) {
            int yy = y + dy;
            if ((unsigned)yy < 64u) {
                const float* row = ib + yy * 64;
#pragma unroll
                for (int dx = -1; dx <= 1; ++dx) {
                    int xx = x + dx;
                    if ((unsigned)xx < 64u) acc += row[xx] * wr[(dy + 1) * 3 + (dx + 1)];
                }
            }
        }
    }
    out[co * NPIX + p] = (acc >= 0.f) ? acc : 0.1f * acc;
}

// ---------------- conv6: 1x1, 64 -> 432, 10*tanh, + flow + bases -> py/px ----------------
__global__ void conv6_off_kernel(const float* __restrict__ in, const float* __restrict__ w,
                                 const float* __restrict__ b, const float* __restrict__ fl0,
                                 float* __restrict__ py, float* __restrict__ px)
{
    __shared__ float wsm[64 * 16];
    const int tid = threadIdx.x;
    const int obase = blockIdx.y * 16;
    for (int idx = tid; idx < 64 * 16; idx += 256) {
        int i = idx >> 4, j = idx & 15;
        wsm[idx] = w[(obase + j) * 64 + i];
    }
    __syncthreads();
    const int p = blockIdx.x * 256 + tid;
    float acc[16];
#pragma unroll
    for (int j = 0; j < 16; ++j) acc[j] = b[obase + j];
    for (int i = 0; i < 64; ++i) {
        float a = in[i * NPIX + p];
        const float* wr = &wsm[i * 16];
#pragma unroll
        for (int j = 0; j < 16; ++j) acc[j] += a * wr[j];
    }
    // fyx = flow0[:, ::-1] -> y gets flow0 ch1, x gets flow0 ch0
    const float f_y = fl0[NPIX + p];
    const float f_x = fl0[p];
    const float yf = (float)(p >> 6), xf = (float)(p & 63);
#pragma unroll
    for (int j = 0; j < 16; ++j) {
        int o = obase + j;
        float val = 10.f * tanhf(acc[j]);
        int s = o >> 1;           // (clip*12+g)*9+a  in [0,216)
        int a_idx = s % 9;
        if ((o & 1) == 0) py[s * NPIX + p] = val + f_y + (float)(a_idx / 3 - 1) + yf;
        else              px[s * NPIX + p] = val + f_x + (float)(a_idx % 3 - 1) + xf;
    }
}

// ---------------- q/k/v projection: 144 -> 288, bf16 out, layout [clip*12+g][pixel][24] ----------------
template <typename T>
__device__ __forceinline__ void proj_acc(const T* __restrict__ ib, int p,
                                         const float* __restrict__ wsm, float* acc)
{
    for (int i = 0; i < 144; ++i) {
        float a = ldf(ib, i * NPIX + p);
        const float* wr = &wsm[i * 24];
#pragma unroll
        for (int j = 0; j < 24; ++j) acc[j] += a * wr[j];
    }
}

__global__ void proj_kernel(const void* __restrict__ in, const float* __restrict__ w,
                            const float* __restrict__ b, const int* __restrict__ flagp,
                            bf16* __restrict__ out)
{
    __shared__ float wsm[144 * 24];
    const int tid = threadIdx.x;
    const int g = blockIdx.y;
    const int clip = blockIdx.z;
    for (int idx = tid; idx < 144 * 24; idx += 256) {
        int i = idx / 24, j = idx - i * 24;
        wsm[idx] = w[i * 288 + g * 24 + j];
    }
    __syncthreads();
    const int p = blockIdx.x * 256 + tid;
    float acc[24];
#pragma unroll
    for (int j = 0; j < 24; ++j) acc[j] = b[g * 24 + j];
    if (flagp[0]) proj_acc<bf16>((const bf16*)in + (size_t)clip * 144 * NPIX, p, wsm, acc);
    else          proj_acc<float>((const float*)in + (size_t)clip * 144 * NPIX, p, wsm, acc);
    bf16* ob = out + ((size_t)(clip * 12 + g) * NPIX + p) * 24;
#pragma unroll
    for (int j = 0; j < 24; ++j) ob[j] = __float2bfloat16(acc[j]);
}

// ---------------- deformable gather + attention ----------------
__global__ void attn_kernel(const bf16* __restrict__ qp, const bf16* __restrict__ kp,
                            const bf16* __restrict__ vp, const float* __restrict__ py,
                            const float* __restrict__ px, bf16* __restrict__ att)
{
    const int t = blockIdx.x * 256 + threadIdx.x;   // 12 heads * 4096 pixels
    const int m = t >> 12;
    const int p = t & 4095;

    float qv[24];
    load24(qp + (size_t)(m * NPIX + p) * 24, qv);

    float sc[18];
    for (int clip = 0; clip < 2; ++clip) {
        const bf16* kb = kp + (size_t)(clip * 12 + m) * NPIX * 24;
        for (int a = 0; a < 9; ++a) {
            const int s = (clip * 12 + m) * 9 + a;
            const float fy = py[s * NPIX + p];
            const float fx = px[s * NPIX + p];
            const float y0 = floorf(fy), x0 = floorf(fx);
            const float wy = fy - y0, wx = fx - x0;
            const int iy = (int)y0, ix = (int)x0;
            float score = 0.f;
            float kf[24];
            if ((unsigned)iy < 64u && (unsigned)ix < 64u) {
                load24(kb + (size_t)(iy * 64 + ix) * 24, kf);
                float d = 0.f;
#pragma unroll
                for (int j = 0; j < 24; ++j) d += qv[j] * kf[j];
                score += (1.f - wy) * (1.f - wx) * d;
            }
            if ((unsigned)iy < 64u && (unsigned)(ix + 1) < 64u) {
                load24(kb + (size_t)(iy * 64 + ix + 1) * 24, kf);
                float d = 0.f;
#pragma unroll
                for (int j = 0; j < 24; ++j) d += qv[j] * kf[j];
                score += (1.f - wy) * wx * d;
            }
            if ((unsigned)(iy + 1) < 64u && (unsigned)ix < 64u) {
                load24(kb + (size_t)((iy + 1) * 64 + ix) * 24, kf);
                float d = 0.f;
#pragma unroll
                for (int j = 0; j < 24; ++j) d += qv[j] * kf[j];
                score += wy * (1.f - wx) * d;
            }
            if ((unsigned)(iy + 1) < 64u && (unsigned)(ix + 1) < 64u) {
                load24(kb + (size_t)((iy + 1) * 64 + ix + 1) * 24, kf);
                float d = 0.f;
#pragma unroll
                for (int j = 0; j < 24; ++j) d += qv[j] * kf[j];
                score += wy * wx * d;
            }
            sc[clip * 9 + a] = score * 0.20412414523193154f;  // 24^-0.5
        }
    }

    float mx = sc[0];
#pragma unroll
    for (int s = 1; s < 18; ++s) mx = fmaxf(mx, sc[s]);
    float sum = 0.f;
#pragma unroll
    for (int s = 0; s < 18; ++s) { sc[s] = expf(sc[s] - mx); sum += sc[s]; }
    const float inv = 1.f / sum;

    float ov[24];
#pragma unroll
    for (int j = 0; j < 24; ++j) ov[j] = 0.f;

    for (int clip = 0; clip < 2; ++clip) {
        const bf16* vb = vp + (size_t)(clip * 12 + m) * NPIX * 24;
        for (int a = 0; a < 9; ++a) {
            const int s = (clip * 12 + m) * 9 + a;
            const float wa = sc[clip * 9 + a] * inv;
            const float fy = py[s * NPIX + p];
            const float fx = px[s * NPIX + p];
            const float y0 = floorf(fy), x0 = floorf(fx);
            const float wy = fy - y0, wx = fx - x0;
            const int iy = (int)y0, ix = (int)x0;
            float vf[24];
            if ((unsigned)iy < 64u && (unsigned)ix < 64u) {
                load24(vb + (size_t)(iy * 64 + ix) * 24, vf);
                float f = wa * (1.f - wy) * (1.f - wx);
#pragma unroll
                for (int j = 0; j < 24; ++j) ov[j] += f * vf[j];
            }
            if ((unsigned)iy < 64u && (unsigned)(ix + 1) < 64u) {
                load24(vb + (size_t)(iy * 64 + ix + 1) * 24, vf);
                float f = wa * (1.f - wy) * wx;
#pragma unroll
                for (int j = 0; j < 24; ++j) ov[j] += f * vf[j];
            }
            if ((unsigned)(iy + 1) < 64u && (unsigned)ix < 64u) {
                load24(vb + (size_t)((iy + 1) * 64 + ix) * 24, vf);
                float f = wa * wy * (1.f - wx);
#pragma unroll
                for (int j = 0; j < 24; ++j) ov[j] += f * vf[j];
            }
            if ((unsigned)(iy + 1) < 64u && (unsigned)(ix + 1) < 64u) {
                load24(vb + (size_t)((iy + 1) * 64 + ix + 1) * 24, vf);
                float f = wa * wy * wx;
#pragma unroll
                for (int j = 0; j < 24; ++j) ov[j] += f * vf[j];
            }
        }
    }
#pragma unroll
    for (int j = 0; j < 24; ++j) att[(size_t)(m * 24 + j) * NPIX + p] = __float2bfloat16(ov[j]);
}

// ---------------- generic channel-linear (input TI, fp32 weights [Cin][Cout]) ----------------
template <typename TI, int CIN, int ACT>
__global__ void linear_kernel(const TI* __restrict__ in, const float* __restrict__ w,
                              const float* __restrict__ b, int cout, float* __restrict__ out)
{
    __shared__ float wsm[CIN * 16];
    const int tid = threadIdx.x;
    const int obase = blockIdx.y * 16;
    for (int idx = tid; idx < CIN * 16; idx += 256) {
        int i = idx >> 4, j = idx & 15;
        wsm[idx] = w[i * cout + obase + j];
    }
    __syncthreads();
    const int p = blockIdx.x * 256 + tid;
    float acc[16];
#pragma unroll
    for (int j = 0; j < 16; ++j) acc[j] = b[obase + j];
    for (int i = 0; i < CIN; ++i) {
        float a = ldf(in, i * NPIX + p);
        const float* wr = &wsm[i * 16];
#pragma unroll
        for (int j = 0; j < 16; ++j) acc[j] += a * wr[j];
    }
#pragma unroll
    for (int j = 0; j < 16; ++j) {
        float v = acc[j];
        if (ACT == 1) v = 0.5f * v * (1.f + erff(v * 0.70710678118654752f));  // exact gelu
        out[(obase + j) * NPIX + p] = v;
    }
}

// ---------------- final: m2 = linear(m1, wm2) ; out = o + m2 (dtype per flag) ----------------
__global__ void final_kernel(const float* __restrict__ m1, const float* __restrict__ w,
                             const float* __restrict__ b, const float* __restrict__ o,
                             const int* __restrict__ flagp, void* __restrict__ outv)
{
    __shared__ float wsm[288 * 16];
    const int tid = threadIdx.x;
    const int obase = blockIdx.y * 16;
    for (int idx = tid; idx < 288 * 16; idx += 256) {
        int i = idx >> 4, j = idx & 15;
        wsm[idx] = w[i * 144 + obase + j];
    }
    __syncthreads();
    const int p = blockIdx.x * 256 + tid;
    float acc[16];
#pragma unroll
    for (int j = 0; j < 16; ++j) acc[j] = b[obase + j];
    for (int i = 0; i < 288; ++i) {
        float a = m1[i * NPIX + p];
        const float* wr = &wsm[i * 16];
#pragma unroll
        for (int j = 0; j < 16; ++j) acc[j] += a * wr[j];
    }
    if (flagp[0]) {
        bf16* out = (bf16*)outv;
#pragma unroll
        for (int j = 0; j < 16; ++j)
            out[(obase + j) * NPIX + p] = __float2bfloat16(acc[j] + o[(obase + j) * NPIX + p]);
    } else {
        float* out = (float*)outv;
#pragma unroll
        for (int j = 0; j < 16; ++j)
            out[(obase + j) * NPIX + p] = acc[j] + o[(obase + j) * NPIX + p];
    }
}

// ---------------- diagnostic: ws too small -> absmax encodes ws MiB ----------------
__global__ void diag_kernel(float* __restrict__ out, int n, float v)
{
    int i = blockIdx.x * 256 + threadIdx.x;
    if (i < n) out[i] = (i == 0 ? v : 0.f);
}

extern "C" void kernel_launch(void* const* d_in, const int* in_sizes, int n_in,
                              void* d_out, int out_size, void* d_ws, size_t ws_size,
                              hipStream_t stream)
{
    // ---- workspace layout (bytes from base), peak 23,115,776 <= proven >=23,592,960 ----
    // [0,64)            flag ints
    // [64, 1881728)     converted fp32 weights/biases/flows (470,416 floats)
    // [1882112, ...)    py fp32 216x4096   (3,538,944 B) -> end 5,421,056
    //                   px fp32            -> end 8,960,000
    //                   qp bf16 12x4096x24 (2,359,296 B) -> end 11,319,296   [o fp32 aliases later]
    //                   kp bf16 24x4096x24 (4,718,592 B) -> end 16,037,888   [m1 fp32 aliases later]
    //                   vp bf16 24x4096x24 (4,718,592 B) -> end 20,756,480
    //                   att bf16 288x4096  (2,359,296 B) -> end 23,115,776   [xA/xB alias during conv phase]
    const size_t REQUIRED = 23115776;
    if (ws_size < REQUIRED) {
        float code = 1000.0f + (float)(ws_size >> 20);
        diag_kernel<<<dim3((out_size + 255) / 256), 256, 0, stream>>>((float*)d_out, out_size, code);
        return;
    }

    char* base = (char*)d_ws;
    int*   flagp = (int*)base;
    float* cw    = (float*)(base + 64);
    float* py    = (float*)(base + 1882112);
    float* px    = (float*)(base + 5421056);
    bf16*  qp    = (bf16*) (base + 8960000);
    bf16*  kp    = (bf16*) (base + 11319296);
    bf16*  vp    = (bf16*) (base + 16037888);
    bf16*  att   = (bf16*) (base + 20756480);
    float* xA    = (float*)(base + 20756480);   // alias att (dead before attn)
    float* xB    = (float*)(base + 21805056);
    float* o     = (float*)(base + 8960000);    // alias qp (dead after attn)
    float* m1    = (float*)(base + 11319296);   // alias kp (dead after attn)

    // converted-weight element offsets
    const int OF_WO1 = 0,      OF_BO1 = 27904,  OF_WO2 = 27968,  OF_BO2 = 64832;
    const int OF_WO3 = 64896,  OF_BO3 = 101760, OF_WO4 = 101824, OF_BO4 = 138688;
    const int OF_WO5 = 138752, OF_BO5 = 175616, OF_WO6 = 175680, OF_BO6 = 203328;
    const int OF_WQ  = 203760, OF_BQ  = 245232, OF_WK  = 245520, OF_BK  = 286992;
    const int OF_WV  = 287280, OF_BV  = 328752, OF_WP  = 329040, OF_BP  = 370512;
    const int OF_WM1 = 370656, OF_BM1 = 412128, OF_WM2 = 412416, OF_BM2 = 453888;
    const int OF_FL0 = 454032, OF_FL1 = 462224;

    detect_kernel<<<1, 256, 0, stream>>>((const unsigned short*)d_in[0], flagp);

    CArgs ca;
    const int srcidx[26] = {7,8,9,10,11,12,13,14,15,16,17,18,19,20,21,22,23,24,25,26,27,28,29,30,5,6};
    const int dsto[26]   = {OF_WO1,OF_BO1,OF_WO2,OF_BO2,OF_WO3,OF_BO3,OF_WO4,OF_BO4,OF_WO5,OF_BO5,
                            OF_WO6,OF_BO6,OF_WQ,OF_BQ,OF_WK,OF_BK,OF_WV,OF_BV,OF_WP,OF_BP,
                            OF_WM1,OF_BM1,OF_WM2,OF_BM2,OF_FL0,OF_FL1};
    for (int i = 0; i < 26; ++i) {
        ca.src[i] = d_in[srcidx[i]];
        ca.dstoff[i] = dsto[i];
        ca.n[i] = in_sizes[srcidx[i]];
    }
    convert_kernel<<<dim3(8, 26), 256, 0, stream>>>(ca, flagp, cw);

    conv1_kernel<<<dim3(16, 4), 256, 0, stream>>>(d_in[0], d_in[3], d_in[4],
                                                  cw + OF_FL0, cw + OF_FL1,
                                                  cw + OF_WO1, cw + OF_BO1, flagp, xA);
    conv3_kernel<<<dim3(16, 64), 256, 0, stream>>>(xA, cw + OF_WO2, cw + OF_BO2, xB);
    conv3_kernel<<<dim3(16, 64), 256, 0, stream>>>(xB, cw + OF_WO3, cw + OF_BO3, xA);
    conv3_kernel<<<dim3(16, 64), 256, 0, stream>>>(xA, cw + OF_WO4, cw + OF_BO4, xB);
    conv3_kernel<<<dim3(16, 64), 256, 0, stream>>>(xB, cw + OF_WO5, cw + OF_BO5, xA);
    conv6_off_kernel<<<dim3(16, 27), 256, 0, stream>>>(xA, cw + OF_WO6, cw + OF_BO6,
                                                       cw + OF_FL0, py, px);

    proj_kernel<<<dim3(16, 12, 1), 256, 0, stream>>>(d_in[0], cw + OF_WQ, cw + OF_BQ, flagp, qp);
    proj_kernel<<<dim3(16, 12, 2), 256, 0, stream>>>(d_in[1], cw + OF_WK, cw + OF_BK, flagp, kp);
    proj_kernel<<<dim3(16, 12, 2), 256, 0, stream>>>(d_in[2], cw + OF_WV, cw + OF_BV, flagp, vp);

    attn_kernel<<<dim3(192), 256, 0, stream>>>(qp, kp, vp, py, px, att);

    linear_kernel<bf16, 288, 0><<<dim3(16, 9), 256, 0, stream>>>(att, cw + OF_WP, cw + OF_BP, 144, o);
    linear_kernel<float, 144, 1><<<dim3(16, 18), 256, 0, stream>>>(o, cw + OF_WM1, cw + OF_BM1, 288, m1);
    final_kernel<<<dim3(16, 9), 256, 0, stream>>>(m1, cw + OF_WM2, cw + OF_BM2, o, flagp, d_out);
}

// Round 4
// 553.305 us; speedup vs baseline: 1.3073x; 1.3073x over previous
//
#include <hip/hip_runtime.h>
#include <hip/hip_bf16.h>
#include <math.h>

typedef __hip_bfloat16 bf16;

#define NPIX 4096

__device__ __forceinline__ float b2f(bf16 v) { return __bfloat162float(v); }
__device__ __forceinline__ float ldf(const bf16* p, int i) { return __bfloat162float(p[i]); }
__device__ __forceinline__ float ldf(const float* p, int i) { return p[i]; }

// Load 24 contiguous bf16 (48 bytes, 16B-aligned) -> 24 floats.
__device__ __forceinline__ void load24(const bf16* __restrict__ src, float* dst) {
    const uint4* s = (const uint4*)src;
#pragma unroll
    for (int c = 0; c < 3; ++c) {
        uint4 u = s[c];
        dst[c * 8 + 0] = __uint_as_float(u.x << 16);
        dst[c * 8 + 1] = __uint_as_float(u.x & 0xFFFF0000u);
        dst[c * 8 + 2] = __uint_as_float(u.y << 16);
        dst[c * 8 + 3] = __uint_as_float(u.y & 0xFFFF0000u);
        dst[c * 8 + 4] = __uint_as_float(u.z << 16);
        dst[c * 8 + 5] = __uint_as_float(u.z & 0xFFFF0000u);
        dst[c * 8 + 6] = __uint_as_float(u.w << 16);
        dst[c * 8 + 7] = __uint_as_float(u.w & 0xFFFF0000u);
    }
}

// ---------------- dtype detector: bf16 vs fp32 input buffers ----------------
__global__ void detect_kernel(const unsigned short* __restrict__ qraw, int* __restrict__ flagp)
{
    __shared__ int cnt;
    if (threadIdx.x == 0) cnt = 0;
    __syncthreads();
    unsigned short u = qraw[threadIdx.x * 2];
    int e = (u >> 7) & 0xFF;
    if (e >= 100 && e <= 135) atomicAdd(&cnt, 1);
    __syncthreads();
    if (threadIdx.x == 0) flagp[0] = (cnt > 128) ? 1 : 0;
}

// ---------------- convert 26 small tensors (weights/biases/flows) to fp32 ----------------
struct CArgs {
    const void* src[26];
    int dstoff[26];
    int n[26];
};

__global__ void convert_kernel(CArgs a, const int* __restrict__ flagp, float* __restrict__ cw)
{
    const int t = blockIdx.y;
    const int n = a.n[t];
    float* d = cw + a.dstoff[t];
    if (flagp[0]) {
        const bf16* s = (const bf16*)a.src[t];
        for (int i = blockIdx.x * 256 + threadIdx.x; i < n; i += 256 * gridDim.x) d[i] = b2f(s[i]);
    } else {
        const float* s = (const float*)a.src[t];
        for (int i = blockIdx.x * 256 + threadIdx.x; i < n; i += 256 * gridDim.x) d[i] = s[i];
    }
}

// ---------------- conv1: 1x1, 436 -> 64, virtual concat, lrelu, 4 outch/thread ----------------
template <typename T>
__device__ __forceinline__ void conv1_body(const T* __restrict__ q, const T* __restrict__ v0,
                                           const T* __restrict__ v1, int p, int og,
                                           const float* __restrict__ w, float* acc)
{
    for (int i = 0; i < 144; ++i) {
        float a = ldf(q, i * NPIX + p);
#pragma unroll
        for (int j = 0; j < 4; ++j) acc[j] += a * w[(og + j) * 436 + i];
    }
    for (int i = 0; i < 144; ++i) {
        float a = ldf(v0, i * NPIX + p);
#pragma unroll
        for (int j = 0; j < 4; ++j) acc[j] += a * w[(og + j) * 436 + 144 + i];
    }
    for (int i = 0; i < 144; ++i) {
        float a = ldf(v1, i * NPIX + p);
#pragma unroll
        for (int j = 0; j < 4; ++j) acc[j] += a * w[(og + j) * 436 + 288 + i];
    }
}

__global__ void conv1_kernel(const void* __restrict__ q, const void* __restrict__ v0,
                             const void* __restrict__ v1, const float* __restrict__ fl0,
                             const float* __restrict__ fl1, const float* __restrict__ w,
                             const float* __restrict__ b, const int* __restrict__ flagp,
                             float* __restrict__ out)
{
    const int tid = threadIdx.x;
    const int og = blockIdx.y * 4;
    const int p = blockIdx.x * 256 + tid;
    float acc[4];
#pragma unroll
    for (int j = 0; j < 4; ++j) acc[j] = b[og + j];
    if (flagp[0]) conv1_body<bf16>((const bf16*)q, (const bf16*)v0, (const bf16*)v1, p, og, w, acc);
    else          conv1_body<float>((const float*)q, (const float*)v0, (const float*)v1, p, og, w, acc);
    float fa[4] = { fl0[p], fl0[NPIX + p], fl1[p], fl1[NPIX + p] };
#pragma unroll
    for (int i = 0; i < 4; ++i) {
#pragma unroll
        for (int j = 0; j < 4; ++j) acc[j] += fa[i] * w[(og + j) * 436 + 432 + i];
    }
#pragma unroll
    for (int j = 0; j < 4; ++j) {
        float v = acc[j];
        out[(og + j) * NPIX + p] = (v >= 0.f) ? v : 0.1f * v;
    }
}

// ---------------- conv 3x3, 64 -> 64, pad 1, lrelu, 4 outch/thread ----------------
__global__ void conv3_kernel(const float* __restrict__ in, const float* __restrict__ w,
                             const float* __restrict__ b, float* __restrict__ out)
{
    const int tid = threadIdx.x;
    const int og = blockIdx.y * 4;
    const int p = blockIdx.x * 256 + tid;
    const int y = p >> 6, x = p & 63;

    int off[9]; float msk[9];
#pragma unroll
    for (int t = 0; t < 9; ++t) {
        int yy = y + t / 3 - 1, xx = x + t % 3 - 1;
        int valid = ((unsigned)yy < 64u) & ((unsigned)xx < 64u);
        int yc = min(max(yy, 0), 63), xc = min(max(xx, 0), 63);
        off[t] = yc * 64 + xc;
        msk[t] = valid ? 1.f : 0.f;
    }

    float a0 = b[og + 0], a1 = b[og + 1], a2 = b[og + 2], a3 = b[og + 3];
    for (int ci = 0; ci < 64; ++ci) {
        const float* ib = in + ci * NPIX;
        float v[9];
#pragma unroll
        for (int t = 0; t < 9; ++t) v[t] = ib[off[t]] * msk[t];
        const int wb = ci * 9;
#pragma unroll
        for (int t = 0; t < 9; ++t) {
            a0 += v[t] * w[(og + 0) * 576 + wb + t];
            a1 += v[t] * w[(og + 1) * 576 + wb + t];
            a2 += v[t] * w[(og + 2) * 576 + wb + t];
            a3 += v[t] * w[(og + 3) * 576 + wb + t];
        }
    }
    out[(og + 0) * NPIX + p] = (a0 >= 0.f) ? a0 : 0.1f * a0;
    out[(og + 1) * NPIX + p] = (a1 >= 0.f) ? a1 : 0.1f * a1;
    out[(og + 2) * NPIX + p] = (a2 >= 0.f) ? a2 : 0.1f * a2;
    out[(og + 3) * NPIX + p] = (a3 >= 0.f) ? a3 : 0.1f * a3;
}

// ---------------- conv6: 1x1, 64 -> 432, 10*tanh, + flow + bases -> py/px, 16 out/thread ----------------
__global__ void conv6_off_kernel(const float* __restrict__ in, const float* __restrict__ w,
                                 const float* __restrict__ b, const float* __restrict__ fl0,
                                 float* __restrict__ py, float* __restrict__ px)
{
    const int tid = threadIdx.x;
    const int obase = blockIdx.y * 16;
    const int p = blockIdx.x * 256 + tid;
    float acc[16];
#pragma unroll
    for (int j = 0; j < 16; ++j) acc[j] = b[obase + j];
    for (int i = 0; i < 64; ++i) {
        float a = in[i * NPIX + p];
#pragma unroll
        for (int j = 0; j < 16; ++j) acc[j] += a * w[(obase + j) * 64 + i];
    }
    const float f_y = fl0[NPIX + p];
    const float f_x = fl0[p];
    const float yf = (float)(p >> 6), xf = (float)(p & 63);
#pragma unroll
    for (int j = 0; j < 16; ++j) {
        int o = obase + j;
        float val = 10.f * tanhf(acc[j]);
        int s = o >> 1;           // (clip*12+g)*9+a  in [0,216)
        int a_idx = s % 9;
        if ((o & 1) == 0) py[s * NPIX + p] = val + f_y + (float)(a_idx / 3 - 1) + yf;
        else              px[s * NPIX + p] = val + f_x + (float)(a_idx % 3 - 1) + xf;
    }
}

// ---------------- q/k/v projection: 144 -> 288, bf16 out, layout [clip*12+g][pixel][24] ----------------
template <typename T>
__device__ __forceinline__ void proj_body(const T* __restrict__ ib, int p, int g,
                                          const float* __restrict__ w, float* acc)
{
    for (int i = 0; i < 144; ++i) {
        float a = ldf(ib, i * NPIX + p);
#pragma unroll
        for (int j = 0; j < 24; ++j) acc[j] += a * w[i * 288 + g * 24 + j];
    }
}

__global__ void proj_kernel(const void* __restrict__ in, const float* __restrict__ w,
                            const float* __restrict__ b, const int* __restrict__ flagp,
                            bf16* __restrict__ out)
{
    const int tid = threadIdx.x;
    const int g = blockIdx.y;
    const int clip = blockIdx.z;
    const int p = blockIdx.x * 256 + tid;
    float acc[24];
#pragma unroll
    for (int j = 0; j < 24; ++j) acc[j] = b[g * 24 + j];
    if (flagp[0]) proj_body<bf16>((const bf16*)in + (size_t)clip * 144 * NPIX, p, g, w, acc);
    else          proj_body<float>((const float*)in + (size_t)clip * 144 * NPIX, p, g, w, acc);
    bf16* ob = out + ((size_t)(clip * 12 + g) * NPIX + p) * 24;
#pragma unroll
    for (int j = 0; j < 24; ++j) ob[j] = __float2bfloat16(acc[j]);
}

// ---------------- deformable gather + attention ----------------
__global__ void attn_kernel(const bf16* __restrict__ qp, const bf16* __restrict__ kp,
                            const bf16* __restrict__ vp, const float* __restrict__ py,
                            const float* __restrict__ px, bf16* __restrict__ att)
{
    const int t = blockIdx.x * 256 + threadIdx.x;   // 12 heads * 4096 pixels
    const int m = t >> 12;
    const int p = t & 4095;

    float qv[24];
    load24(qp + (size_t)(m * NPIX + p) * 24, qv);

    float sc[18];
    for (int clip = 0; clip < 2; ++clip) {
        const bf16* kb = kp + (size_t)(clip * 12 + m) * NPIX * 24;
        for (int a = 0; a < 9; ++a) {
            const int s = (clip * 12 + m) * 9 + a;
            const float fy = py[s * NPIX + p];
            const float fx = px[s * NPIX + p];
            const float y0 = floorf(fy), x0 = floorf(fx);
            const float wy = fy - y0, wx = fx - x0;
            const int iy = (int)y0, ix = (int)x0;
            float score = 0.f;
            float kf[24];
            if ((unsigned)iy < 64u && (unsigned)ix < 64u) {
                load24(kb + (size_t)(iy * 64 + ix) * 24, kf);
                float d = 0.f;
#pragma unroll
                for (int j = 0; j < 24; ++j) d += qv[j] * kf[j];
                score += (1.f - wy) * (1.f - wx) * d;
            }
            if ((unsigned)iy < 64u && (unsigned)(ix + 1) < 64u) {
                load24(kb + (size_t)(iy * 64 + ix + 1) * 24, kf);
                float d = 0.f;
#pragma unroll
                for (int j = 0; j < 24; ++j) d += qv[j] * kf[j];
                score += (1.f - wy) * wx * d;
            }
            if ((unsigned)(iy + 1) < 64u && (unsigned)ix < 64u) {
                load24(kb + (size_t)((iy + 1) * 64 + ix) * 24, kf);
                float d = 0.f;
#pragma unroll
                for (int j = 0; j < 24; ++j) d += qv[j] * kf[j];
                score += wy * (1.f - wx) * d;
            }
            if ((unsigned)(iy + 1) < 64u && (unsigned)(ix + 1) < 64u) {
                load24(kb + (size_t)((iy + 1) * 64 + ix + 1) * 24, kf);
                float d = 0.f;
#pragma unroll
                for (int j = 0; j < 24; ++j) d += qv[j] * kf[j];
                score += wy * wx * d;
            }
            sc[clip * 9 + a] = score * 0.20412414523193154f;  // 24^-0.5
        }
    }

    float mx = sc[0];
#pragma unroll
    for (int s = 1; s < 18; ++s) mx = fmaxf(mx, sc[s]);
    float sum = 0.f;
#pragma unroll
    for (int s = 0; s < 18; ++s) { sc[s] = expf(sc[s] - mx); sum += sc[s]; }
    const float inv = 1.f / sum;

    float ov[24];
#pragma unroll
    for (int j = 0; j < 24; ++j) ov[j] = 0.f;

    for (int clip = 0; clip < 2; ++clip) {
        const bf16* vb = vp + (size_t)(clip * 12 + m) * NPIX * 24;
        for (int a = 0; a < 9; ++a) {
            const int s = (clip * 12 + m) * 9 + a;
            const float wa = sc[clip * 9 + a] * inv;
            const float fy = py[s * NPIX + p];
            const float fx = px[s * NPIX + p];
            const float y0 = floorf(fy), x0 = floorf(fx);
            const float wy = fy - y0, wx = fx - x0;
            const int iy = (int)y0, ix = (int)x0;
            float vf[24];
            if ((unsigned)iy < 64u && (unsigned)ix < 64u) {
                load24(vb + (size_t)(iy * 64 + ix) * 24, vf);
                float f = wa * (1.f - wy) * (1.f - wx);
#pragma unroll
                for (int j = 0; j < 24; ++j) ov[j] += f * vf[j];
            }
            if ((unsigned)iy < 64u && (unsigned)(ix + 1) < 64u) {
                load24(vb + (size_t)(iy * 64 + ix + 1) * 24, vf);
                float f = wa * (1.f - wy) * wx;
#pragma unroll
                for (int j = 0; j < 24; ++j) ov[j] += f * vf[j];
            }
            if ((unsigned)(iy + 1) < 64u && (unsigned)ix < 64u) {
                load24(vb + (size_t)((iy + 1) * 64 + ix) * 24, vf);
                float f = wa * wy * (1.f - wx);
#pragma unroll
                for (int j = 0; j < 24; ++j) ov[j] += f * vf[j];
            }
            if ((unsigned)(iy + 1) < 64u && (unsigned)(ix + 1) < 64u) {
                load24(vb + (size_t)((iy + 1) * 64 + ix + 1) * 24, vf);
                float f = wa * wy * wx;
#pragma unroll
                for (int j = 0; j < 24; ++j) ov[j] += f * vf[j];
            }
        }
    }
#pragma unroll
    for (int j = 0; j < 24; ++j) att[(size_t)(m * 24 + j) * NPIX + p] = __float2bfloat16(ov[j]);
}

// ---------------- generic channel-linear, 8 out/thread (weights fp32 [Cin][Cout]) ----------------
template <typename TI, int CIN, int ACT>
__global__ void linear_kernel(const TI* __restrict__ in, const float* __restrict__ w,
                              const float* __restrict__ b, int cout, float* __restrict__ out)
{
    const int tid = threadIdx.x;
    const int og = blockIdx.y * 8;
    const int p = blockIdx.x * 256 + tid;
    float acc[8];
#pragma unroll
    for (int j = 0; j < 8; ++j) acc[j] = b[og + j];
    for (int i = 0; i < CIN; ++i) {
        float a = ldf(in, i * NPIX + p);
#pragma unroll
        for (int j = 0; j < 8; ++j) acc[j] += a * w[i * cout + og + j];
    }
#pragma unroll
    for (int j = 0; j < 8; ++j) {
        float v = acc[j];
        if (ACT == 1) v = 0.5f * v * (1.f + erff(v * 0.70710678118654752f));  // exact gelu
        out[(og + j) * NPIX + p] = v;
    }
}

// ---------------- final: m2 = linear(m1, wm2) ; out = o + m2 (dtype per flag), 8 out/thread ----------------
__global__ void final_kernel(const float* __restrict__ m1, const float* __restrict__ w,
                             const float* __restrict__ b, const float* __restrict__ o,
                             const int* __restrict__ flagp, void* __restrict__ outv)
{
    const int tid = threadIdx.x;
    const int og = blockIdx.y * 8;
    const int p = blockIdx.x * 256 + tid;
    float acc[8];
#pragma unroll
    for (int j = 0; j < 8; ++j) acc[j] = b[og + j];
    for (int i = 0; i < 288; ++i) {
        float a = m1[i * NPIX + p];
#pragma unroll
        for (int j = 0; j < 8; ++j) acc[j] += a * w[i * 144 + og + j];
    }
    if (flagp[0]) {
        bf16* out = (bf16*)outv;
#pragma unroll
        for (int j = 0; j < 8; ++j)
            out[(og + j) * NPIX + p] = __float2bfloat16(acc[j] + o[(og + j) * NPIX + p]);
    } else {
        float* out = (float*)outv;
#pragma unroll
        for (int j = 0; j < 8; ++j)
            out[(og + j) * NPIX + p] = acc[j] + o[(og + j) * NPIX + p];
    }
}

// ---------------- diagnostic ----------------
__global__ void diag_kernel(float* __restrict__ out, int n, float v)
{
    int i = blockIdx.x * 256 + threadIdx.x;
    if (i < n) out[i] = (i == 0 ? v : 0.f);
}

extern "C" void kernel_launch(void* const* d_in, const int* in_sizes, int n_in,
                              void* d_out, int out_size, void* d_ws, size_t ws_size,
                              hipStream_t stream)
{
    const size_t REQUIRED = 23115776;
    if (ws_size < REQUIRED) {
        float code = 1000.0f + (float)(ws_size >> 20);
        diag_kernel<<<dim3((out_size + 255) / 256), 256, 0, stream>>>((float*)d_out, out_size, code);
        return;
    }

    char* base = (char*)d_ws;
    int*   flagp = (int*)base;
    float* cw    = (float*)(base + 64);
    float* py    = (float*)(base + 1882112);
    float* px    = (float*)(base + 5421056);
    bf16*  qp    = (bf16*) (base + 8960000);
    bf16*  kp    = (bf16*) (base + 11319296);
    bf16*  vp    = (bf16*) (base + 16037888);
    bf16*  att   = (bf16*) (base + 20756480);
    float* xA    = (float*)(base + 20756480);   // alias att (dead before attn)
    float* xB    = (float*)(base + 21805056);
    float* o     = (float*)(base + 8960000);    // alias qp (dead after attn)
    float* m1    = (float*)(base + 11319296);   // alias kp (dead after attn)

    const int OF_WO1 = 0,      OF_BO1 = 27904,  OF_WO2 = 27968,  OF_BO2 = 64832;
    const int OF_WO3 = 64896,  OF_BO3 = 101760, OF_WO4 = 101824, OF_BO4 = 138688;
    const int OF_WO5 = 138752, OF_BO5 = 175616, OF_WO6 = 175680, OF_BO6 = 203328;
    const int OF_WQ  = 203760, OF_BQ  = 245232, OF_WK  = 245520, OF_BK  = 286992;
    const int OF_WV  = 287280, OF_BV  = 328752, OF_WP  = 329040, OF_BP  = 370512;
    const int OF_WM1 = 370656, OF_BM1 = 412128, OF_WM2 = 412416, OF_BM2 = 453888;
    const int OF_FL0 = 454032, OF_FL1 = 462224;

    detect_kernel<<<1, 256, 0, stream>>>((const unsigned short*)d_in[0], flagp);

    CArgs ca;
    const int srcidx[26] = {7,8,9,10,11,12,13,14,15,16,17,18,19,20,21,22,23,24,25,26,27,28,29,30,5,6};
    const int dsto[26]   = {OF_WO1,OF_BO1,OF_WO2,OF_BO2,OF_WO3,OF_BO3,OF_WO4,OF_BO4,OF_WO5,OF_BO5,
                            OF_WO6,OF_BO6,OF_WQ,OF_BQ,OF_WK,OF_BK,OF_WV,OF_BV,OF_WP,OF_BP,
                            OF_WM1,OF_BM1,OF_WM2,OF_BM2,OF_FL0,OF_FL1};
    for (int i = 0; i < 26; ++i) {
        ca.src[i] = d_in[srcidx[i]];
        ca.dstoff[i] = dsto[i];
        ca.n[i] = in_sizes[srcidx[i]];
    }
    convert_kernel<<<dim3(8, 26), 256, 0, stream>>>(ca, flagp, cw);

    conv1_kernel<<<dim3(16, 16), 256, 0, stream>>>(d_in[0], d_in[3], d_in[4],
                                                   cw + OF_FL0, cw + OF_FL1,
                                                   cw + OF_WO1, cw + OF_BO1, flagp, xA);
    conv3_kernel<<<dim3(16, 16), 256, 0, stream>>>(xA, cw + OF_WO2, cw + OF_BO2, xB);
    conv3_kernel<<<dim3(16, 16), 256, 0, stream>>>(xB, cw + OF_WO3, cw + OF_BO3, xA);
    conv3_kernel<<<dim3(16, 16), 256, 0, stream>>>(xA, cw + OF_WO4, cw + OF_BO4, xB);
    conv3_kernel<<<dim3(16, 16), 256, 0, stream>>>(xB, cw + OF_WO5, cw + OF_BO5, xA);
    conv6_off_kernel<<<dim3(16, 27), 256, 0, stream>>>(xA, cw + OF_WO6, cw + OF_BO6,
                                                       cw + OF_FL0, py, px);

    proj_kernel<<<dim3(16, 12, 1), 256, 0, stream>>>(d_in[0], cw + OF_WQ, cw + OF_BQ, flagp, qp);
    proj_kernel<<<dim3(16, 12, 2), 256, 0, stream>>>(d_in[1], cw + OF_WK, cw + OF_BK, flagp, kp);
    proj_kernel<<<dim3(16, 12, 2), 256, 0, stream>>>(d_in[2], cw + OF_WV, cw + OF_BV, flagp, vp);

    attn_kernel<<<dim3(192), 256, 0, stream>>>(qp, kp, vp, py, px, att);

    linear_kernel<bf16, 288, 0><<<dim3(16, 18), 256, 0, stream>>>(att, cw + OF_WP, cw + OF_BP, 144, o);
    linear_kernel<float, 144, 1><<<dim3(16, 36), 256, 0, stream>>>(o, cw + OF_WM1, cw + OF_BM1, 288, m1);
    final_kernel<<<dim3(16, 18), 256, 0, stream>>>(m1, cw + OF_WM2, cw + OF_BM2, o, flagp, d_out);
}

// Round 5
// 411.768 us; speedup vs baseline: 1.7566x; 1.3437x over previous
//
#include <hip/hip_runtime.h>
#include <hip/hip_bf16.h>
#include <math.h>

typedef __hip_bfloat16 bf16;

#define NPIX 4096

__device__ __forceinline__ float b2f(bf16 v) { return __bfloat162float(v); }
__device__ __forceinline__ float ldf(const bf16* p, int i) { return __bfloat162float(p[i]); }
__device__ __forceinline__ float ldf(const float* p, int i) { return p[i]; }

__device__ __forceinline__ unsigned short f2bu(float f) {
    bf16 h = __float2bfloat16(f);
    return *(unsigned short*)&h;
}

// Wave-inline dtype detector: true if buffer is bf16. Uniform per wave.
__device__ __forceinline__ int detect_bf16(const unsigned short* __restrict__ qraw) {
    int lane = threadIdx.x & 63;
    unsigned short u = qraw[lane * 2];
    int e = (u >> 7) & 0xFF;
    unsigned long long ball = __ballot(e >= 100 && e <= 135);
    return __popcll(ball) > 32;
}

// dot of 12 bf16 (24B, 8B-aligned) with qv[12]
__device__ __forceinline__ float dot12(const bf16* __restrict__ row, const float* qv) {
    const uint2* s = (const uint2*)row;
    float d = 0.f;
#pragma unroll
    for (int c = 0; c < 3; ++c) {
        uint2 u = s[c];
        d += qv[c * 4 + 0] * __uint_as_float(u.x << 16);
        d += qv[c * 4 + 1] * __uint_as_float(u.x & 0xFFFF0000u);
        d += qv[c * 4 + 2] * __uint_as_float(u.y << 16);
        d += qv[c * 4 + 3] * __uint_as_float(u.y & 0xFFFF0000u);
    }
    return d;
}

__device__ __forceinline__ void acc12(float* ov, const bf16* __restrict__ row, float f) {
    const uint2* s = (const uint2*)row;
#pragma unroll
    for (int c = 0; c < 3; ++c) {
        uint2 u = s[c];
        ov[c * 4 + 0] += f * __uint_as_float(u.x << 16);
        ov[c * 4 + 1] += f * __uint_as_float(u.x & 0xFFFF0000u);
        ov[c * 4 + 2] += f * __uint_as_float(u.y << 16);
        ov[c * 4 + 3] += f * __uint_as_float(u.y & 0xFFFF0000u);
    }
}

// ---------------- convert 26 small tensors to fp32 ----------------
struct CArgs {
    const void* src[26];
    int dstoff[26];
    int n[26];
};

__global__ void convert_kernel(CArgs a, const unsigned short* __restrict__ qraw,
                               float* __restrict__ cw)
{
    const int isbf = detect_bf16(qraw);
    const int t = blockIdx.y;
    const int n = a.n[t];
    float* d = cw + a.dstoff[t];
    if (isbf) {
        const bf16* s = (const bf16*)a.src[t];
        for (int i = blockIdx.x * 256 + threadIdx.x; i < n; i += 256 * gridDim.x) d[i] = b2f(s[i]);
    } else {
        const float* s = (const float*)a.src[t];
        for (int i = blockIdx.x * 256 + threadIdx.x; i < n; i += 256 * gridDim.x) d[i] = s[i];
    }
}

// ---------------- conv1: 1x1, 436 -> 64, virtual concat, lrelu, 2 outch/thread ----------------
template <typename T>
__device__ __forceinline__ void conv1_body(const T* __restrict__ q, const T* __restrict__ v0,
                                           const T* __restrict__ v1, int p, int og,
                                           const float* __restrict__ w, float* acc)
{
    for (int i = 0; i < 144; ++i) {
        float a = ldf(q, i * NPIX + p);
        acc[0] += a * w[og * 436 + i];
        acc[1] += a * w[(og + 1) * 436 + i];
    }
    for (int i = 0; i < 144; ++i) {
        float a = ldf(v0, i * NPIX + p);
        acc[0] += a * w[og * 436 + 144 + i];
        acc[1] += a * w[(og + 1) * 436 + 144 + i];
    }
    for (int i = 0; i < 144; ++i) {
        float a = ldf(v1, i * NPIX + p);
        acc[0] += a * w[og * 436 + 288 + i];
        acc[1] += a * w[(og + 1) * 436 + 288 + i];
    }
}

__global__ void conv1_kernel(const void* __restrict__ q, const void* __restrict__ v0,
                             const void* __restrict__ v1, const float* __restrict__ fl0,
                             const float* __restrict__ fl1, const float* __restrict__ w,
                             const float* __restrict__ b, float* __restrict__ out)
{
    const int isbf = detect_bf16((const unsigned short*)q);
    const int og = blockIdx.y * 2;
    const int p = blockIdx.x * 256 + threadIdx.x;
    float acc[2] = { b[og], b[og + 1] };
    if (isbf) conv1_body<bf16>((const bf16*)q, (const bf16*)v0, (const bf16*)v1, p, og, w, acc);
    else      conv1_body<float>((const float*)q, (const float*)v0, (const float*)v1, p, og, w, acc);
    float fa[4] = { fl0[p], fl0[NPIX + p], fl1[p], fl1[NPIX + p] };
#pragma unroll
    for (int i = 0; i < 4; ++i) {
        acc[0] += fa[i] * w[og * 436 + 432 + i];
        acc[1] += fa[i] * w[(og + 1) * 436 + 432 + i];
    }
#pragma unroll
    for (int j = 0; j < 2; ++j) {
        float v = acc[j];
        out[(og + j) * NPIX + p] = (v >= 0.f) ? v : 0.1f * v;
    }
}

// ---------------- conv 3x3, 64 -> 64, pad 1, lrelu, 2 outch/thread ----------------
__global__ void conv3_kernel(const float* __restrict__ in, const float* __restrict__ w,
                             const float* __restrict__ b, float* __restrict__ out)
{
    const int og = blockIdx.y * 2;
    const int p = blockIdx.x * 256 + threadIdx.x;
    const int y = p >> 6, x = p & 63;

    int off[9]; float msk[9];
#pragma unroll
    for (int t = 0; t < 9; ++t) {
        int yy = y + t / 3 - 1, xx = x + t % 3 - 1;
        int valid = ((unsigned)yy < 64u) & ((unsigned)xx < 64u);
        int yc = min(max(yy, 0), 63), xc = min(max(xx, 0), 63);
        off[t] = yc * 64 + xc;
        msk[t] = valid ? 1.f : 0.f;
    }

    float a0 = b[og], a1 = b[og + 1];
    for (int ci = 0; ci < 64; ++ci) {
        const float* ib = in + ci * NPIX;
        float v[9];
#pragma unroll
        for (int t = 0; t < 9; ++t) v[t] = ib[off[t]] * msk[t];
        const int wb = ci * 9;
#pragma unroll
        for (int t = 0; t < 9; ++t) {
            a0 += v[t] * w[og * 576 + wb + t];
            a1 += v[t] * w[(og + 1) * 576 + wb + t];
        }
    }
    out[og * NPIX + p] = (a0 >= 0.f) ? a0 : 0.1f * a0;
    out[(og + 1) * NPIX + p] = (a1 >= 0.f) ? a1 : 0.1f * a1;
}

// ---------------- conv6: 1x1, 64 -> 432, 10*tanh, + flow + bases -> py/px, 8 out/thread ----------------
__global__ void conv6_off_kernel(const float* __restrict__ in, const float* __restrict__ w,
                                 const float* __restrict__ b, const float* __restrict__ fl0,
                                 float* __restrict__ py, float* __restrict__ px)
{
    const int obase = blockIdx.y * 8;
    const int p = blockIdx.x * 256 + threadIdx.x;
    float acc[8];
#pragma unroll
    for (int j = 0; j < 8; ++j) acc[j] = b[obase + j];
    for (int i = 0; i < 64; ++i) {
        float a = in[i * NPIX + p];
#pragma unroll
        for (int j = 0; j < 8; ++j) acc[j] += a * w[(obase + j) * 64 + i];
    }
    const float f_y = fl0[NPIX + p];
    const float f_x = fl0[p];
    const float yf = (float)(p >> 6), xf = (float)(p & 63);
#pragma unroll
    for (int j = 0; j < 8; ++j) {
        int o = obase + j;
        float val = 10.f * tanhf(acc[j]);
        int s = o >> 1;           // (clip*12+g)*9+a  in [0,216)
        int a_idx = s % 9;
        if ((o & 1) == 0) py[s * NPIX + p] = val + f_y + (float)(a_idx / 3 - 1) + yf;
        else              px[s * NPIX + p] = val + f_x + (float)(a_idx % 3 - 1) + xf;
    }
}

// ---------------- fused q/k/v projection: 5 z-slices, 8 out/thread ----------------
struct PS { const void* src; const float* w; const float* b; bf16* dst; int clip; };
struct PArgs { PS s[5]; };

template <typename T>
__device__ __forceinline__ void proj_body(const T* __restrict__ ib, int p, int og,
                                          const float* __restrict__ w, float* acc)
{
    for (int i = 0; i < 144; ++i) {
        float a = ldf(ib, i * NPIX + p);
#pragma unroll
        for (int j = 0; j < 8; ++j) acc[j] += a * w[i * 288 + og + j];
    }
}

__global__ void proj_kernel(PArgs pa, const unsigned short* __restrict__ qraw)
{
    const int isbf = detect_bf16(qraw);
    const PS ps = pa.s[blockIdx.z];
    const int og = blockIdx.y * 8;          // 0..280, never crosses a 24-boundary
    const int p = blockIdx.x * 256 + threadIdx.x;
    float acc[8];
#pragma unroll
    for (int j = 0; j < 8; ++j) acc[j] = ps.b[og + j];
    if (isbf) proj_body<bf16>((const bf16*)ps.src + (size_t)ps.clip * 144 * NPIX, p, og, ps.w, acc);
    else      proj_body<float>((const float*)ps.src + (size_t)ps.clip * 144 * NPIX, p, og, ps.w, acc);
    const int g = og / 24, cj = og % 24;
    bf16* ob = ps.dst + ((size_t)(ps.clip * 12 + g) * NPIX + p) * 24 + cj;
    uint4 u;
    u.x = ((unsigned)f2bu(acc[1]) << 16) | f2bu(acc[0]);
    u.y = ((unsigned)f2bu(acc[3]) << 16) | f2bu(acc[2]);
    u.z = ((unsigned)f2bu(acc[5]) << 16) | f2bu(acc[4]);
    u.w = ((unsigned)f2bu(acc[7]) << 16) | f2bu(acc[6]);
    *(uint4*)ob = u;
}

// ---------------- deformable gather + attention, 4-thread teams ----------------
// team: t&1 = channel half (12 ch), (t>>1)&1 = clip; (t>>2) -> (m, p)
__global__ __launch_bounds__(256) void attn_kernel(
    const bf16* __restrict__ qp, const bf16* __restrict__ kp,
    const bf16* __restrict__ vp, const float* __restrict__ py,
    const float* __restrict__ px, bf16* __restrict__ att)
{
    const int t = blockIdx.x * 256 + threadIdx.x;
    const int ch = t & 1;
    const int clip = (t >> 1) & 1;
    const int pp = t >> 2;
    const int m = pp >> 12;
    const int p = pp & 4095;

    float qv[12];
    {
        const uint2* s = (const uint2*)(qp + (size_t)(m * 4096 + p) * 24 + ch * 12);
#pragma unroll
        for (int c = 0; c < 3; ++c) {
            uint2 u = s[c];
            qv[c * 4 + 0] = __uint_as_float(u.x << 16);
            qv[c * 4 + 1] = __uint_as_float(u.x & 0xFFFF0000u);
            qv[c * 4 + 2] = __uint_as_float(u.y << 16);
            qv[c * 4 + 3] = __uint_as_float(u.y & 0xFFFF0000u);
        }
    }

    const int gidx = clip * 12 + m;
    const bf16* kb = kp + (size_t)gidx * 4096 * 24 + ch * 12;
    const bf16* vb = vp + (size_t)gidx * 4096 * 24 + ch * 12;
    const int sbase = gidx * 9;

    float e[9];
    float mx = -1e30f;
#pragma unroll
    for (int a = 0; a < 9; ++a) {
        const float fy = py[(sbase + a) * NPIX + p];
        const float fx = px[(sbase + a) * NPIX + p];
        const float y0 = floorf(fy), x0 = floorf(fx);
        const float wy = fy - y0, wx = fx - x0;
        const int iy = (int)y0, ix = (int)x0;
        const float w00 = (1.f - wy) * (1.f - wx), w01 = (1.f - wy) * wx;
        const float w10 = wy * (1.f - wx), w11 = wy * wx;
        float part = 0.f;
        if ((unsigned)iy < 64u) {
            const bf16* r = kb + (size_t)(iy * 64) * 24;
            if ((unsigned)ix < 64u)       part += w00 * dot12(r + ix * 24, qv);
            if ((unsigned)(ix + 1) < 64u) part += w01 * dot12(r + (ix + 1) * 24, qv);
        }
        if ((unsigned)(iy + 1) < 64u) {
            const bf16* r = kb + (size_t)((iy + 1) * 64) * 24;
            if ((unsigned)ix < 64u)       part += w10 * dot12(r + ix * 24, qv);
            if ((unsigned)(ix + 1) < 64u) part += w11 * dot12(r + (ix + 1) * 24, qv);
        }
        float full = part + __shfl_xor(part, 1, 64);
        e[a] = full * 0.20412414523193154f;   // 24^-0.5
        mx = fmaxf(mx, e[a]);
    }
    mx = fmaxf(mx, __shfl_xor(mx, 2, 64));
    float sum = 0.f;
#pragma unroll
    for (int a = 0; a < 9; ++a) { e[a] = __expf(e[a] - mx); sum += e[a]; }
    sum += __shfl_xor(sum, 2, 64);
    const float inv = 1.f / sum;

    float ov[12];
#pragma unroll
    for (int j = 0; j < 12; ++j) ov[j] = 0.f;

#pragma unroll
    for (int a = 0; a < 9; ++a) {
        const float wa = e[a] * inv;
        const float fy = py[(sbase + a) * NPIX + p];
        const float fx = px[(sbase + a) * NPIX + p];
        const float y0 = floorf(fy), x0 = floorf(fx);
        const float wy = fy - y0, wx = fx - x0;
        const int iy = (int)y0, ix = (int)x0;
        if ((unsigned)iy < 64u) {
            const bf16* r = vb + (size_t)(iy * 64) * 24;
            if ((unsigned)ix < 64u)       acc12(ov, r + ix * 24, wa * (1.f - wy) * (1.f - wx));
            if ((unsigned)(ix + 1) < 64u) acc12(ov, r + (ix + 1) * 24, wa * (1.f - wy) * wx);
        }
        if ((unsigned)(iy + 1) < 64u) {
            const bf16* r = vb + (size_t)((iy + 1) * 64) * 24;
            if ((unsigned)ix < 64u)       acc12(ov, r + ix * 24, wa * wy * (1.f - wx));
            if ((unsigned)(ix + 1) < 64u) acc12(ov, r + (ix + 1) * 24, wa * wy * wx);
        }
    }
#pragma unroll
    for (int j = 0; j < 12; ++j) ov[j] += __shfl_xor(ov[j], 2, 64);
    if (clip == 0) {
#pragma unroll
        for (int j = 0; j < 12; ++j)
            att[(size_t)(m * 24 + ch * 12 + j) * NPIX + p] = __float2bfloat16(ov[j]);
    }
}

// ---------------- generic channel-linear, 4 out/thread ----------------
template <typename TI, int CIN, int ACT>
__global__ void linear_kernel(const TI* __restrict__ in, const float* __restrict__ w,
                              const float* __restrict__ b, int cout, float* __restrict__ out)
{
    const int og = blockIdx.y * 4;
    const int p = blockIdx.x * 256 + threadIdx.x;
    float acc[4];
#pragma unroll
    for (int j = 0; j < 4; ++j) acc[j] = b[og + j];
    for (int i = 0; i < CIN; ++i) {
        float a = ldf(in, i * NPIX + p);
#pragma unroll
        for (int j = 0; j < 4; ++j) acc[j] += a * w[i * cout + og + j];
    }
#pragma unroll
    for (int j = 0; j < 4; ++j) {
        float v = acc[j];
        if (ACT == 1) v = 0.5f * v * (1.f + erff(v * 0.70710678118654752f));  // exact gelu
        out[(og + j) * NPIX + p] = v;
    }
}

// ---------------- final: m2 = linear(m1, wm2); out = o + m2 (dtype per flag), 4 out/thread ----------------
__global__ void final_kernel(const float* __restrict__ m1, const float* __restrict__ w,
                             const float* __restrict__ b, const float* __restrict__ o,
                             const unsigned short* __restrict__ qraw, void* __restrict__ outv)
{
    const int isbf = detect_bf16(qraw);
    const int og = blockIdx.y * 4;
    const int p = blockIdx.x * 256 + threadIdx.x;
    float acc[4];
#pragma unroll
    for (int j = 0; j < 4; ++j) acc[j] = b[og + j];
    for (int i = 0; i < 288; ++i) {
        float a = m1[i * NPIX + p];
#pragma unroll
        for (int j = 0; j < 4; ++j) acc[j] += a * w[i * 144 + og + j];
    }
    if (isbf) {
        bf16* out = (bf16*)outv;
#pragma unroll
        for (int j = 0; j < 4; ++j)
            out[(og + j) * NPIX + p] = __float2bfloat16(acc[j] + o[(og + j) * NPIX + p]);
    } else {
        float* out = (float*)outv;
#pragma unroll
        for (int j = 0; j < 4; ++j)
            out[(og + j) * NPIX + p] = acc[j] + o[(og + j) * NPIX + p];
    }
}

// ---------------- diagnostic ----------------
__global__ void diag_kernel(float* __restrict__ out, int n, float v)
{
    int i = blockIdx.x * 256 + threadIdx.x;
    if (i < n) out[i] = (i == 0 ? v : 0.f);
}

extern "C" void kernel_launch(void* const* d_in, const int* in_sizes, int n_in,
                              void* d_out, int out_size, void* d_ws, size_t ws_size,
                              hipStream_t stream)
{
    const size_t REQUIRED = 23115776;
    if (ws_size < REQUIRED) {
        float code = 1000.0f + (float)(ws_size >> 20);
        diag_kernel<<<dim3((out_size + 255) / 256), 256, 0, stream>>>((float*)d_out, out_size, code);
        return;
    }

    char* base = (char*)d_ws;
    float* cw    = (float*)(base + 64);
    float* py    = (float*)(base + 1882112);
    float* px    = (float*)(base + 5421056);
    bf16*  qp    = (bf16*) (base + 8960000);
    bf16*  kp    = (bf16*) (base + 11319296);
    bf16*  vp    = (bf16*) (base + 16037888);
    bf16*  att   = (bf16*) (base + 20756480);
    float* xA    = (float*)(base + 20756480);   // alias att (dead before attn)
    float* xB    = (float*)(base + 21805056);
    float* o     = (float*)(base + 8960000);    // alias qp (dead after attn)
    float* m1    = (float*)(base + 11319296);   // alias kp (dead after attn)

    const int OF_WO1 = 0,      OF_BO1 = 27904,  OF_WO2 = 27968,  OF_BO2 = 64832;
    const int OF_WO3 = 64896,  OF_BO3 = 101760, OF_WO4 = 101824, OF_BO4 = 138688;
    const int OF_WO5 = 138752, OF_BO5 = 175616, OF_WO6 = 175680, OF_BO6 = 203328;
    const int OF_WQ  = 203760, OF_BQ  = 245232, OF_WK  = 245520, OF_BK  = 286992;
    const int OF_WV  = 287280, OF_BV  = 328752, OF_WP  = 329040, OF_BP  = 370512;
    const int OF_WM1 = 370656, OF_BM1 = 412128, OF_WM2 = 412416, OF_BM2 = 453888;
    const int OF_FL0 = 454032, OF_FL1 = 462224;

    const unsigned short* qraw = (const unsigned short*)d_in[0];

    CArgs ca;
    const int srcidx[26] = {7,8,9,10,11,12,13,14,15,16,17,18,19,20,21,22,23,24,25,26,27,28,29,30,5,6};
    const int dsto[26]   = {OF_WO1,OF_BO1,OF_WO2,OF_BO2,OF_WO3,OF_BO3,OF_WO4,OF_BO4,OF_WO5,OF_BO5,
                            OF_WO6,OF_BO6,OF_WQ,OF_BQ,OF_WK,OF_BK,OF_WV,OF_BV,OF_WP,OF_BP,
                            OF_WM1,OF_BM1,OF_WM2,OF_BM2,OF_FL0,OF_FL1};
    for (int i = 0; i < 26; ++i) {
        ca.src[i] = d_in[srcidx[i]];
        ca.dstoff[i] = dsto[i];
        ca.n[i] = in_sizes[srcidx[i]];
    }
    convert_kernel<<<dim3(8, 26), 256, 0, stream>>>(ca, qraw, cw);

    conv1_kernel<<<dim3(16, 32), 256, 0, stream>>>(d_in[0], d_in[3], d_in[4],
                                                   cw + OF_FL0, cw + OF_FL1,
                                                   cw + OF_WO1, cw + OF_BO1, xA);
    conv3_kernel<<<dim3(16, 32), 256, 0, stream>>>(xA, cw + OF_WO2, cw + OF_BO2, xB);
    conv3_kernel<<<dim3(16, 32), 256, 0, stream>>>(xB, cw + OF_WO3, cw + OF_BO3, xA);
    conv3_kernel<<<dim3(16, 32), 256, 0, stream>>>(xA, cw + OF_WO4, cw + OF_BO4, xB);
    conv3_kernel<<<dim3(16, 32), 256, 0, stream>>>(xB, cw + OF_WO5, cw + OF_BO5, xA);
    conv6_off_kernel<<<dim3(16, 54), 256, 0, stream>>>(xA, cw + OF_WO6, cw + OF_BO6,
                                                       cw + OF_FL0, py, px);

    PArgs pa;
    pa.s[0] = { d_in[0], cw + OF_WQ, cw + OF_BQ, qp, 0 };
    pa.s[1] = { d_in[1], cw + OF_WK, cw + OF_BK, kp, 0 };
    pa.s[2] = { d_in[1], cw + OF_WK, cw + OF_BK, kp, 1 };
    pa.s[3] = { d_in[2], cw + OF_WV, cw + OF_BV, vp, 0 };
    pa.s[4] = { d_in[2], cw + OF_WV, cw + OF_BV, vp, 1 };
    proj_kernel<<<dim3(16, 36, 5), 256, 0, stream>>>(pa, qraw);

    attn_kernel<<<dim3(768), 256, 0, stream>>>(qp, kp, vp, py, px, att);

    linear_kernel<bf16, 288, 0><<<dim3(16, 36), 256, 0, stream>>>(att, cw + OF_WP, cw + OF_BP, 144, o);
    linear_kernel<float, 144, 1><<<dim3(16, 72), 256, 0, stream>>>(o, cw + OF_WM1, cw + OF_BM1, 288, m1);
    final_kernel<<<dim3(16, 36), 256, 0, stream>>>(m1, cw + OF_WM2, cw + OF_BM2, o, qraw, d_out);
}